// Round 9
// baseline (647.758 us; speedup 1.0000x reference)
//
#include <hip/hip_runtime.h>
#include <stdint.h>

typedef __attribute__((ext_vector_type(8))) short bf16x8;
typedef __attribute__((ext_vector_type(4))) float f32x4;

__device__ __forceinline__ unsigned short f2bf(float f){
  union { float f; unsigned u; } v; v.f = f;
  return (unsigned short)((v.u + 0x7fffu + ((v.u >> 16) & 1u)) >> 16);
}
__device__ __forceinline__ float bf2f(unsigned short h){
  union { unsigned u; float f; } v; v.u = ((unsigned)h) << 16; return v.f;
}
__device__ __forceinline__ void gload16(const void* g, void* lds){
  __builtin_amdgcn_global_load_lds((const __attribute__((address_space(1))) unsigned int*)g,
                                   (__attribute__((address_space(3))) unsigned int*)lds,
                                   16, 0, 0);
}
#define MFMA(a,b,c) __builtin_amdgcn_mfma_f32_16x16x32_bf16((a),(b),(c),0,0,0)

// B=8, H=W=64, N=4096, C=512, nh=8, hd=64

__global__ void k_conv_x(const float* __restrict__ x, unsigned short* __restrict__ xb, int n){
  int i = (blockIdx.x*256 + threadIdx.x)*8;
  if (i >= n) return;
  float4 a = *(const float4*)(x+i);
  float4 b = *(const float4*)(x+i+4);
  *(ushort4*)(xb+i)   = make_ushort4(f2bf(a.x), f2bf(a.y), f2bf(a.z), f2bf(a.w));
  *(ushort4*)(xb+i+4) = make_ushort4(f2bf(b.x), f2bf(b.y), f2bf(b.z), f2bf(b.w));
}

// wqkv[1536][512] bf16; wsp2[512][2048] bf16 = [Whi|Whi|Wlo|Wlo]
__global__ void k_conv_w(const float* __restrict__ Wq, const float* __restrict__ Wkv,
                         const float* __restrict__ Wp,
                         unsigned short* __restrict__ wqkv, unsigned short* __restrict__ wsp2){
  int i = blockIdx.x*256 + threadIdx.x;
  int stride = gridDim.x*256;
  for (int e = i; e < 1536*512; e += stride){
    int r = e >> 9;
    wqkv[e] = f2bf(r < 512 ? Wq[e] : Wkv[e - 512*512]);
  }
  for (int e = i; e < 512*2048; e += stride){
    int o = e >> 11, kk = e & 2047;
    float wv = Wp[(o << 9) + (kk & 511)];
    unsigned short hi = f2bf(wv);
    wsp2[e] = (kk < 1024) ? hi : f2bf(wv - bf2f(hi));
  }
}

// bias64: heads 1..5 (p=4 strip-grouped-with-mask, p=8). bias256: heads 6,7 (p=16).
__global__ void k_bias(const float* t1,const float* t2,const float* t3,const float* t4,
                       const float* t5,const float* t6,const float* t7,
                       float* __restrict__ b64, float* __restrict__ b256){
  int i = blockIdx.x*256 + threadIdx.x;
  int stride = gridDim.x*256;
  for (int e = i; e < 5*4096; e += stride){
    int hh = e >> 12;
    int q = (e >> 6) & 63, kk = e & 63;
    float v;
    if (hh < 2){
      const float* tb = hh ? t2 : t1;
      int r1=q>>4, i1=(q>>2)&3, c1=q&3;
      int r2=kk>>4, i2=(kk>>2)&3, c2=kk&3;
      v = (i1==i2) ? tb[(r1-r2+3)*7 + (c1-c2+3)] : -1e30f;
    } else {
      const float* tb = (hh==2)?t3:((hh==3)?t4:t5);
      int r1=q>>3, c1=q&7, r2=kk>>3, c2=kk&7;
      v = tb[(r1-r2+7)*15 + (c1-c2+7)];
    }
    b64[e] = v;
  }
  for (int e = i; e < 2*65536; e += stride){
    int hh = e >> 16; int q = (e >> 8) & 255, kk = e & 255;
    const float* tb = hh ? t7 : t6;
    int r1=q>>4, c1=q&15, r2=kk>>4, c2=kk&15;
    b256[e] = tb[(r1-r2+15)*31 + (c1-c2+15)];
  }
}

// ---------- GEMM (validated) ----------
template<int EPI>
__global__ __launch_bounds__(256, 2)
void k_gemm(const unsigned short* __restrict__ A, const unsigned short* __restrict__ Bw,
            int M,
            unsigned short* __restrict__ oq, unsigned short* __restrict__ ok,
            unsigned short* __restrict__ ovt,
            float* __restrict__ of, const float* __restrict__ bias)
{
  __shared__ unsigned short As[128*64];
  __shared__ unsigned short Bs[128*64];
  const int t = threadIdx.x, l = t & 63, w = t >> 6;
  const int mt = M >> 7;
  const int bm = blockIdx.x % mt, bn = blockIdx.x / mt;
  const int m0 = bm << 7, n0 = bn << 7;
  const int wr = w >> 1, wc = w & 1;
  const int lr = l & 15, lg = l >> 4;
  const int KL = (EPI == 0) ? 512 : 2048;
  f32x4 acc[4][4] = {};

  for (int k0 = 0; k0 < KL; k0 += 64){
    #pragma unroll
    for (int i = 0; i < 4; i++){
      int rowb = i*32 + w*8;
      int row  = rowb + (l >> 3);
      int sc   = (((l & 7) ^ (row & 7)) << 3);
      if (EPI == 0)
        gload16(A + (size_t)(m0 + row)*512 + k0 + sc, &As[rowb*64]);
      else
        gload16(A + (size_t)(m0 + row)*1024 + ((k0 & 1023) + sc), &As[rowb*64]);
      gload16(Bw + (size_t)(n0 + row)*KL + k0 + sc, &Bs[rowb*64]);
    }
    __syncthreads();
    #pragma unroll
    for (int kt = 0; kt < 2; kt++){
      bf16x8 af[4], bfr[4];
      #pragma unroll
      for (int mi = 0; mi < 4; mi++){
        int row = wr*64 + mi*16 + lr;
        int cb  = (kt*64 + lg*16) ^ ((row & 7) << 4);
        af[mi] = *(const bf16x8*)((const char*)As + row*128 + cb);
      }
      #pragma unroll
      for (int ni = 0; ni < 4; ni++){
        int row = wc*64 + ni*16 + lr;
        int cb  = (kt*64 + lg*16) ^ ((row & 7) << 4);
        bfr[ni] = *(const bf16x8*)((const char*)Bs + row*128 + cb);
      }
      #pragma unroll
      for (int mi = 0; mi < 4; mi++)
        #pragma unroll
        for (int ni = 0; ni < 4; ni++)
          acc[mi][ni] = MFMA(af[mi], bfr[ni], acc[mi][ni]);
    }
    __syncthreads();
  }

  #pragma unroll
  for (int mi = 0; mi < 4; mi++){
    #pragma unroll
    for (int ni = 0; ni < 4; ni++){
      int m = m0 + wr*64 + mi*16 + lg*4;
      int o = n0 + wc*64 + ni*16 + lr;
      if (EPI == 0){
        int which = o >> 9, oo = o & 511, h = oo >> 6, d = oo & 63;
        int b_ = m >> 12, n_ = m & 4095;
        if (which == 2){
          *(ushort4*)(ovt + ((((size_t)b_*8 + h)*64 + d) << 12) + n_) =
            make_ushort4(f2bf(acc[mi][ni][0]), f2bf(acc[mi][ni][1]),
                         f2bf(acc[mi][ni][2]), f2bf(acc[mi][ni][3]));
        } else {
          unsigned short* dst = (which == 0) ? oq : ok;
          size_t base = (((size_t)(b_*8 + h)) << 18) + ((size_t)n_ << 6) + d;
          #pragma unroll
          for (int r = 0; r < 4; r++)
            dst[base + (size_t)r*64] = f2bf(acc[mi][ni][r]);
        }
      } else {
        float bv = bias[o];
        #pragma unroll
        for (int r = 0; r < 4; r++)
          of[(size_t)(m + r)*512 + o] = acc[mi][ni][r] + bv;
      }
    }
  }
}

// ---------- flash: 8 independent waves/block, register-direct K/V, no barriers ----------
// Block = (b, h0:(win,chunk) | h67:(h,win)); wave w = q-subtile of 32 rows.
// All 8 waves share the block's K/V chunk -> L1 8x reuse; cross-block reuse via L2 (XCD pin).
// h0: 8 KV steps -> bf16 partial O + f32 partial l. h67: 4 steps -> fsp direct.
// No max tracking (|score| bounded); lsum via ones-column MFMA; P via wave-private LDS.
__device__ __forceinline__ int map16(int win, int t){
  return (((win >> 2)*16 + (t >> 4)) << 6) + ((win & 3) << 4) + (t & 15);
}

__global__ __launch_bounds__(512, 5)
void k_flash(const unsigned short* __restrict__ qb, const unsigned short* __restrict__ kb,
             const unsigned short* __restrict__ vtb, const float* __restrict__ b256,
             unsigned short* __restrict__ fsp,
             unsigned short* __restrict__ pO, float* __restrict__ pl)
{
  __shared__ unsigned short Pp[8][2048];           // per-wave P: 32x64 bf16
  const int t = threadIdx.x, l = t & 63, w = t >> 6;
  const int lr = l & 15, lg = l >> 4;
  const int v = (blockIdx.x & 7)*160 + (blockIdx.x >> 3);   // XCD-pinned, 1280 blocks
  const int b = v / 160, u = v % 160;
  int h, win, s0, s1, chunk = 0;
  const float* btab = nullptr;
  if (u < 128){ h = 0; win = u >> 3; chunk = u & 7; s0 = chunk*8; s1 = s0 + 8; }
  else { int uu = u - 128; h = 6 + (uu >> 4); win = uu & 15; s0 = 0; s1 = 4;
         btab = b256 + ((size_t)(h - 6) << 16); }
  const size_t hb = ((size_t)(b*8 + h)) << 18;

  char* pw = (char*)Pp[w];
  bf16x8 ones8;
  #pragma unroll
  for (int e = 0; e < 8; e++) ones8[e] = (short)0x3F80;    // bf16 1.0

  bf16x8 qf[2][2];
  #pragma unroll
  for (int mf = 0; mf < 2; mf++){
    int qt = w*32 + mf*16 + lr;
    int n = (h == 0) ? (win*256 + qt) : map16(win, qt);
    const unsigned short* qp = qb + hb + ((size_t)n << 6) + lg*8;
    qf[mf][0] = *(const bf16x8*)qp;
    qf[mf][1] = *(const bf16x8*)(qp + 32);
  }
  f32x4 ao[2][4] = {};
  f32x4 lsum4[2] = {};

  for (int s = s0; s < s1; s++){
    // QK^T: K fragments straight from global (d-contiguous 16B)
    f32x4 sv[2][4] = {};
    #pragma unroll
    for (int kt = 0; kt < 2; kt++){
      bf16x8 kf[4];
      #pragma unroll
      for (int nf = 0; nf < 4; nf++){
        int tk = s*64 + nf*16 + lr;
        int nk = (h == 0) ? tk : map16(win, tk);
        kf[nf] = *(const bf16x8*)(kb + hb + ((size_t)nk << 6) + kt*32 + lg*8);
      }
      #pragma unroll
      for (int mf = 0; mf < 2; mf++)
        #pragma unroll
        for (int nf = 0; nf < 4; nf++)
          sv[mf][nf] = MFMA(qf[mf][kt], kf[nf], sv[mf][nf]);
    }
    // scale + bias + exp (no shift), pack P -> wave-private LDS (swizzled)
    #pragma unroll
    for (int mf = 0; mf < 2; mf++)
      #pragma unroll
      for (int nf = 0; nf < 4; nf++)
        #pragma unroll
        for (int r = 0; r < 4; r++){
          float x = sv[mf][nf][r] * 0.125f;
          if (btab){
            int qw = w*32 + mf*16 + lg*4 + r;
            int kw = s*64 + nf*16 + lr;
            x += btab[(qw << 8) + kw];
          }
          float p = __expf(x);
          int row = mf*16 + lg*4 + r;
          int cb  = ((nf*16 + lr)*2) ^ ((row & 7) << 4);
          *(unsigned short*)(pw + row*128 + cb) = f2bf(p);
        }
    // PV: V^T fragments straight from global (n-contiguous 16B); lsum via ones-MFMA
    #pragma unroll
    for (int kg = 0; kg < 2; kg++){
      bf16x8 pa[2], vf[4];
      #pragma unroll
      for (int mf = 0; mf < 2; mf++){
        int row = mf*16 + lr;
        int cb  = (kg*64 + lg*16) ^ ((row & 7) << 4);
        pa[mf] = *(const bf16x8*)(pw + row*128 + cb);
      }
      int tv = s*64 + kg*32 + lg*8;
      int nv = (h == 0) ? tv : map16(win, tv);
      #pragma unroll
      for (int df = 0; df < 4; df++)
        vf[df] = *(const bf16x8*)(vtb + hb + ((size_t)(df*16 + lr) << 12) + nv);
      #pragma unroll
      for (int mf = 0; mf < 2; mf++){
        #pragma unroll
        for (int df = 0; df < 4; df++)
          ao[mf][df] = MFMA(pa[mf], vf[df], ao[mf][df]);
        lsum4[mf] = MFMA(pa[mf], ones8, lsum4[mf]);
      }
    }
  }

  if (h == 0){
    // pO row = (b*8 + chunk)*4096 + n, n = win*256 + qt
    #pragma unroll
    for (int mf = 0; mf < 2; mf++)
      #pragma unroll
      for (int r = 0; r < 4; r++){
        int qt = w*32 + mf*16 + lg*4 + r;
        size_t rowb = (((size_t)(b*8 + chunk)) << 12) + win*256 + qt;
        if (lr == 0) pl[rowb] = lsum4[mf][r];
        #pragma unroll
        for (int df = 0; df < 4; df++)
          pO[(rowb << 6) + df*16 + lr] = f2bf(ao[mf][df][r]);
      }
  } else {
    #pragma unroll
    for (int mf = 0; mf < 2; mf++)
      #pragma unroll
      for (int df = 0; df < 4; df++)
        #pragma unroll
        for (int r = 0; r < 4; r++){
          float o = ao[mf][df][r] / lsum4[mf][r];
          int qt = w*32 + mf*16 + lg*4 + r;
          int np = win*256 + qt;
          size_t base = (((size_t)b*4096 + np) << 10) + h*64 + df*16 + lr;
          unsigned short hi = f2bf(o);
          fsp[base] = hi;
          fsp[base + 512] = f2bf(o - bf2f(hi));
        }
  }
}

// ---------- combine head-0 KV chunks (plain sums) ----------
__global__ __launch_bounds__(256)
void k_comb(const unsigned short* __restrict__ pO, const float* __restrict__ pl,
            unsigned short* __restrict__ fsp){
  int tid = blockIdx.x*256 + threadIdx.x;      // 2M = 32768 rows * 64 d
  int d = tid & 63;
  int row = tid >> 6;
  int b = row >> 12;
  int n = row & 4095;
  float o = 0.f, L = 0.f;
  #pragma unroll
  for (int c = 0; c < 8; c++){
    size_t rr = (((size_t)(b*8 + c)) << 12) + n;
    L += pl[rr];
    o += bf2f(pO[(rr << 6) + d]);
  }
  o /= L;
  size_t base = (((size_t)b*4096 + n) << 10) + d;
  unsigned short hi = f2bf(o);
  fsp[base] = hi;
  fsp[base + 512] = f2bf(o - bf2f(hi));
}

// ---------- 64-token window attention (heads 1..5), validated ----------
__device__ __forceinline__ int mapw(int h, int u, int t){
  if (h <= 2) return (((u >> 2)*4 + (t >> 4)) << 6) + ((u & 3) << 4) + (t & 15);
  return (((u >> 3)*8 + (t >> 3)) << 6) + ((u & 7) << 3) + (t & 7);
}

__global__ __launch_bounds__(256, 2)
void k_win64(const unsigned short* __restrict__ qb, const unsigned short* __restrict__ kb,
             const unsigned short* __restrict__ vtb, const float* __restrict__ b64,
             unsigned short* __restrict__ fsp)
{
  __shared__ unsigned short KP[4][64*64];
  __shared__ unsigned short Vw[4][64*64];
  const int t = threadIdx.x, l = t & 63, w = t >> 6;
  const int lr = l & 15, lg = l >> 4;
  const int gid = blockIdx.x*4 + w;
  const int b = gid / 320;
  const int rem = gid % 320;
  const int h = 1 + (rem >> 6);
  const int u = rem & 63;
  const size_t hb = ((size_t)(b*8 + h)) << 18;

  #pragma unroll
  for (int i = 0; i < 8; i++){
    int row = i*8 + (l >> 3);
    int sc  = (((l & 7) ^ (row & 7)) << 3);
    gload16(kb  + hb + ((size_t)mapw(h,u,row) << 6) + sc, &KP[w][i*512]);
    gload16(vtb + hb + ((size_t)row << 12) + mapw(h,u,sc), &Vw[w][i*512]);
  }
  bf16x8 qf[4][2];
  #pragma unroll
  for (int mf = 0; mf < 4; mf++){
    int n = mapw(h, u, mf*16 + lr);
    const unsigned short* qp = qb + hb + ((size_t)n << 6) + lg*8;
    qf[mf][0] = *(const bf16x8*)qp;
    qf[mf][1] = *(const bf16x8*)(qp + 32);
  }
  __syncthreads();

  const char* kpc = (const char*)KP[w];
  const char* vwc = (const char*)Vw[w];
  f32x4 sv[4][4] = {};
  #pragma unroll
  for (int kt = 0; kt < 2; kt++){
    bf16x8 kf[4];
    #pragma unroll
    for (int nf = 0; nf < 4; nf++){
      int row = nf*16 + lr;
      int cb  = (kt*64 + lg*16) ^ ((row & 7) << 4);
      kf[nf] = *(const bf16x8*)(kpc + row*128 + cb);
    }
    #pragma unroll
    for (int mf = 0; mf < 4; mf++)
      #pragma unroll
      for (int nf = 0; nf < 4; nf++)
        sv[mf][nf] = MFMA(qf[mf][kt], kf[nf], sv[mf][nf]);
  }
  const float* bt = b64 + ((size_t)(h-1) << 12);
  float li[4][4];
  #pragma unroll
  for (int mf = 0; mf < 4; mf++)
    #pragma unroll
    for (int r = 0; r < 4; r++){
      int qt = mf*16 + lg*4 + r;
      #pragma unroll
      for (int nf = 0; nf < 4; nf++)
        sv[mf][nf][r] = sv[mf][nf][r]*0.125f + bt[(qt << 6) + nf*16 + lr];
      float mx = fmaxf(fmaxf(sv[mf][0][r], sv[mf][1][r]), fmaxf(sv[mf][2][r], sv[mf][3][r]));
      mx = fmaxf(mx, __shfl_xor(mx, 1));
      mx = fmaxf(mx, __shfl_xor(mx, 2));
      mx = fmaxf(mx, __shfl_xor(mx, 4));
      mx = fmaxf(mx, __shfl_xor(mx, 8));
      float rs = 0.f;
      #pragma unroll
      for (int nf = 0; nf < 4; nf++){
        float p = __expf(sv[mf][nf][r] - mx);
        sv[mf][nf][r] = p; rs += p;
      }
      rs += __shfl_xor(rs, 1); rs += __shfl_xor(rs, 2);
      rs += __shfl_xor(rs, 4); rs += __shfl_xor(rs, 8);
      li[mf][r] = rs;
    }
  char* pw = (char*)KP[w];
  #pragma unroll
  for (int mf = 0; mf < 4; mf++)
    #pragma unroll
    for (int nf = 0; nf < 4; nf++)
      #pragma unroll
      for (int r = 0; r < 4; r++){
        int row = mf*16 + lg*4 + r;
        int cb  = ((nf*16 + lr)*2) ^ ((row & 7) << 4);
        *(unsigned short*)(pw + row*128 + cb) = f2bf(sv[mf][nf][r]);
      }
  f32x4 ao[4][4] = {};
  #pragma unroll
  for (int kg = 0; kg < 2; kg++){
    bf16x8 pa[4], vf[4];
    #pragma unroll
    for (int mf = 0; mf < 4; mf++){
      int row = mf*16 + lr;
      int cb  = (kg*64 + lg*16) ^ ((row & 7) << 4);
      pa[mf] = *(const bf16x8*)(pw + row*128 + cb);
    }
    #pragma unroll
    for (int df = 0; df < 4; df++){
      int row = df*16 + lr;
      int cb  = (kg*64 + lg*16) ^ ((row & 7) << 4);
      vf[df] = *(const bf16x8*)(vwc + row*128 + cb);
    }
    #pragma unroll
    for (int mf = 0; mf < 4; mf++)
      #pragma unroll
      for (int df = 0; df < 4; df++)
        ao[mf][df] = MFMA(pa[mf], vf[df], ao[mf][df]);
  }
  #pragma unroll
  for (int mf = 0; mf < 4; mf++)
    #pragma unroll
    for (int df = 0; df < 4; df++)
      #pragma unroll
      for (int r = 0; r < 4; r++){
        float o = ao[mf][df][r] / li[mf][r];
        int qt = mf*16 + lg*4 + r;
        int np;
        if (h <= 2){
          int r4 = qt >> 4, w_ = (qt >> 2) & 3, c = qt & 3;
          np = (u >> 2)*256 + (u & 3)*64 + w_*16 + r4*4 + c;
        } else {
          np = u*64 + qt;
        }
        size_t base = (((size_t)b*4096 + np) << 10) + h*64 + df*16 + lr;
        unsigned short hi = f2bf(o);
        fsp[base] = hi;
        fsp[base + 512] = f2bf(o - bf2f(hi));
      }
}

// ---------- launch ----------
extern "C" void kernel_launch(void* const* d_in, const int* in_sizes, int n_in,
                              void* d_out, int out_size, void* d_ws, size_t ws_size,
                              hipStream_t stream) {
  const float* x     = (const float*)d_in[0];
  const float* Wq    = (const float*)d_in[1];
  const float* Wkv   = (const float*)d_in[2];
  const float* Wp    = (const float*)d_in[3];
  const float* bproj = (const float*)d_in[4];
  const float* t1 = (const float*)d_in[7];
  const float* t2 = (const float*)d_in[8];
  const float* t3 = (const float*)d_in[9];
  const float* t4 = (const float*)d_in[10];
  const float* t5 = (const float*)d_in[11];
  const float* t6 = (const float*)d_in[12];
  const float* t7 = (const float*)d_in[13];

  char* W = (char*)d_ws;
  size_t off = 0;
  auto alloc = [&](size_t bytes)->char*{
    char* p = W + off; off += (bytes + 255) & ~(size_t)255; return p;
  };
  unsigned short* xb   = (unsigned short*)alloc((size_t)32768*512*2);   // dead after gemm0
  unsigned short* wqkv = (unsigned short*)alloc((size_t)1536*512*2);    // dead after gemm0
  unsigned short* wsp2 = (unsigned short*)alloc((size_t)512*2048*2);
  unsigned short* qbuf = (unsigned short*)alloc((size_t)8*8*4096*64*2);
  unsigned short* kbuf = (unsigned short*)alloc((size_t)8*8*4096*64*2);
  unsigned short* vtb  = (unsigned short*)alloc((size_t)8*8*4096*64*2);
  unsigned short* fsp  = (unsigned short*)alloc((size_t)32768*1024*2);
  float* b64  = (float*)alloc((size_t)5*64*64*4);
  float* b256 = (float*)alloc((size_t)2*256*256*4);
  if (off > ws_size) return;

  // head-0 partials alias dead regions (flash runs after gemm0):
  unsigned short* pO = xb;                 // (8b*8c)*4096 rows * 64 d * 2B = 32 MiB
  float* pl = (float*)wqkv;                // 64*4096*4B = 1 MiB

  k_conv_x<<<8192, 256, 0, stream>>>(x, xb, 32768*512);
  k_conv_w<<<640, 256, 0, stream>>>(Wq, Wkv, Wp, wqkv, wsp2);
  k_bias<<<64, 256, 0, stream>>>(t1,t2,t3,t4,t5,t6,t7, b64, b256);

  k_gemm<0><<<3072, 256, 0, stream>>>(xb, wqkv, 32768,
                                      qbuf, kbuf, vtb, nullptr, nullptr);
  k_flash<<<1280, 512, 0, stream>>>(qbuf, kbuf, vtb, b256, fsp, pO, pl);
  k_comb<<<8192, 256, 0, stream>>>(pO, pl, fsp);
  k_win64<<<640, 256, 0, stream>>>(qbuf, kbuf, vtb, b64, fsp);
  k_gemm<1><<<1024, 256, 0, stream>>>(fsp, wsp2, 32768,
                                      nullptr, nullptr, nullptr, (float*)d_out, bproj);
}

// Round 10
// 402.323 us; speedup vs baseline: 1.6100x; 1.6100x over previous
//
#include <hip/hip_runtime.h>
#include <stdint.h>

typedef __attribute__((ext_vector_type(8))) short bf16x8;
typedef __attribute__((ext_vector_type(4))) float f32x4;

__device__ __forceinline__ unsigned short f2bf(float f){
  union { float f; unsigned u; } v; v.f = f;
  return (unsigned short)((v.u + 0x7fffu + ((v.u >> 16) & 1u)) >> 16);
}
__device__ __forceinline__ float bf2f(unsigned short h){
  union { unsigned u; float f; } v; v.u = ((unsigned)h) << 16; return v.f;
}
__device__ __forceinline__ void gload16(const void* g, void* lds){
  __builtin_amdgcn_global_load_lds((const __attribute__((address_space(1))) unsigned int*)g,
                                   (__attribute__((address_space(3))) unsigned int*)lds,
                                   16, 0, 0);
}
#define MFMA(a,b,c) __builtin_amdgcn_mfma_f32_16x16x32_bf16((a),(b),(c),0,0,0)

// B=8, H=W=64, N=4096, C=512, nh=8, hd=64

__global__ void k_conv_x(const float* __restrict__ x, unsigned short* __restrict__ xb, int n){
  int i = (blockIdx.x*256 + threadIdx.x)*8;
  if (i >= n) return;
  float4 a = *(const float4*)(x+i);
  float4 b = *(const float4*)(x+i+4);
  *(ushort4*)(xb+i)   = make_ushort4(f2bf(a.x), f2bf(a.y), f2bf(a.z), f2bf(a.w));
  *(ushort4*)(xb+i+4) = make_ushort4(f2bf(b.x), f2bf(b.y), f2bf(b.z), f2bf(b.w));
}

// wqkv[1536][512] bf16; wsp2[512][2048] bf16 = [Whi|Whi|Wlo|Wlo]
__global__ void k_conv_w(const float* __restrict__ Wq, const float* __restrict__ Wkv,
                         const float* __restrict__ Wp,
                         unsigned short* __restrict__ wqkv, unsigned short* __restrict__ wsp2){
  int i = blockIdx.x*256 + threadIdx.x;
  int stride = gridDim.x*256;
  for (int e = i; e < 1536*512; e += stride){
    int r = e >> 9;
    wqkv[e] = f2bf(r < 512 ? Wq[e] : Wkv[e - 512*512]);
  }
  for (int e = i; e < 512*2048; e += stride){
    int o = e >> 11, kk = e & 2047;
    float wv = Wp[(o << 9) + (kk & 511)];
    unsigned short hi = f2bf(wv);
    wsp2[e] = (kk < 1024) ? hi : f2bf(wv - bf2f(hi));
  }
}

// bias64: heads 1..5 (p=4 strip-grouped-with-mask, p=8). bias256: heads 6,7 (p=16).
__global__ void k_bias(const float* t1,const float* t2,const float* t3,const float* t4,
                       const float* t5,const float* t6,const float* t7,
                       float* __restrict__ b64, float* __restrict__ b256){
  int i = blockIdx.x*256 + threadIdx.x;
  int stride = gridDim.x*256;
  for (int e = i; e < 5*4096; e += stride){
    int hh = e >> 12;
    int q = (e >> 6) & 63, kk = e & 63;
    float v;
    if (hh < 2){
      const float* tb = hh ? t2 : t1;
      int r1=q>>4, i1=(q>>2)&3, c1=q&3;
      int r2=kk>>4, i2=(kk>>2)&3, c2=kk&3;
      v = (i1==i2) ? tb[(r1-r2+3)*7 + (c1-c2+3)] : -1e30f;
    } else {
      const float* tb = (hh==2)?t3:((hh==3)?t4:t5);
      int r1=q>>3, c1=q&7, r2=kk>>3, c2=kk&7;
      v = tb[(r1-r2+7)*15 + (c1-c2+7)];
    }
    b64[e] = v;
  }
  for (int e = i; e < 2*65536; e += stride){
    int hh = e >> 16; int q = (e >> 8) & 255, kk = e & 255;
    const float* tb = hh ? t7 : t6;
    int r1=q>>4, c1=q&15, r2=kk>>4, c2=kk&15;
    b256[e] = tb[(r1-r2+15)*31 + (c1-c2+15)];
  }
}

// ---------- GEMM (validated) ----------
template<int EPI>
__global__ __launch_bounds__(256, 2)
void k_gemm(const unsigned short* __restrict__ A, const unsigned short* __restrict__ Bw,
            int M,
            unsigned short* __restrict__ oq, unsigned short* __restrict__ ok,
            unsigned short* __restrict__ ovt,
            float* __restrict__ of, const float* __restrict__ bias)
{
  __shared__ unsigned short As[128*64];
  __shared__ unsigned short Bs[128*64];
  const int t = threadIdx.x, l = t & 63, w = t >> 6;
  const int mt = M >> 7;
  const int bm = blockIdx.x % mt, bn = blockIdx.x / mt;
  const int m0 = bm << 7, n0 = bn << 7;
  const int wr = w >> 1, wc = w & 1;
  const int lr = l & 15, lg = l >> 4;
  const int KL = (EPI == 0) ? 512 : 2048;
  f32x4 acc[4][4] = {};

  for (int k0 = 0; k0 < KL; k0 += 64){
    #pragma unroll
    for (int i = 0; i < 4; i++){
      int rowb = i*32 + w*8;
      int row  = rowb + (l >> 3);
      int sc   = (((l & 7) ^ (row & 7)) << 3);
      if (EPI == 0)
        gload16(A + (size_t)(m0 + row)*512 + k0 + sc, &As[rowb*64]);
      else
        gload16(A + (size_t)(m0 + row)*1024 + ((k0 & 1023) + sc), &As[rowb*64]);
      gload16(Bw + (size_t)(n0 + row)*KL + k0 + sc, &Bs[rowb*64]);
    }
    __syncthreads();
    #pragma unroll
    for (int kt = 0; kt < 2; kt++){
      bf16x8 af[4], bfr[4];
      #pragma unroll
      for (int mi = 0; mi < 4; mi++){
        int row = wr*64 + mi*16 + lr;
        int cb  = (kt*64 + lg*16) ^ ((row & 7) << 4);
        af[mi] = *(const bf16x8*)((const char*)As + row*128 + cb);
      }
      #pragma unroll
      for (int ni = 0; ni < 4; ni++){
        int row = wc*64 + ni*16 + lr;
        int cb  = (kt*64 + lg*16) ^ ((row & 7) << 4);
        bfr[ni] = *(const bf16x8*)((const char*)Bs + row*128 + cb);
      }
      #pragma unroll
      for (int mi = 0; mi < 4; mi++)
        #pragma unroll
        for (int ni = 0; ni < 4; ni++)
          acc[mi][ni] = MFMA(af[mi], bfr[ni], acc[mi][ni]);
    }
    __syncthreads();
  }

  #pragma unroll
  for (int mi = 0; mi < 4; mi++){
    #pragma unroll
    for (int ni = 0; ni < 4; ni++){
      int m = m0 + wr*64 + mi*16 + lg*4;
      int o = n0 + wc*64 + ni*16 + lr;
      if (EPI == 0){
        int which = o >> 9, oo = o & 511, h = oo >> 6, d = oo & 63;
        int b_ = m >> 12, n_ = m & 4095;
        if (which == 2){
          *(ushort4*)(ovt + ((((size_t)b_*8 + h)*64 + d) << 12) + n_) =
            make_ushort4(f2bf(acc[mi][ni][0]), f2bf(acc[mi][ni][1]),
                         f2bf(acc[mi][ni][2]), f2bf(acc[mi][ni][3]));
        } else {
          unsigned short* dst = (which == 0) ? oq : ok;
          size_t base = (((size_t)(b_*8 + h)) << 18) + ((size_t)n_ << 6) + d;
          #pragma unroll
          for (int r = 0; r < 4; r++)
            dst[base + (size_t)r*64] = f2bf(acc[mi][ni][r]);
        }
      } else {
        float bv = bias[o];
        #pragma unroll
        for (int r = 0; r < 4; r++)
          of[(size_t)(m + r)*512 + o] = acc[mi][ni][r] + bv;
      }
    }
  }
}

// ---------- flash: 8 independent waves/block, register-direct K/V, no barriers ----------
// Identical to R9 except __launch_bounds__(512, 2): R9's (512,5) forced VGPR=48 and
// spilled ~1.1 GB of scratch traffic (FETCH 637MB/WRITE 486MB). This lets VGPR~120.
__device__ __forceinline__ int map16(int win, int t){
  return (((win >> 2)*16 + (t >> 4)) << 6) + ((win & 3) << 4) + (t & 15);
}

__global__ __launch_bounds__(512, 2)
void k_flash(const unsigned short* __restrict__ qb, const unsigned short* __restrict__ kb,
             const unsigned short* __restrict__ vtb, const float* __restrict__ b256,
             unsigned short* __restrict__ fsp,
             unsigned short* __restrict__ pO, float* __restrict__ pl)
{
  __shared__ unsigned short Pp[8][2048];           // per-wave P: 32x64 bf16
  const int t = threadIdx.x, l = t & 63, w = t >> 6;
  const int lr = l & 15, lg = l >> 4;
  const int v = (blockIdx.x & 7)*160 + (blockIdx.x >> 3);   // XCD-pinned, 1280 blocks
  const int b = v / 160, u = v % 160;
  int h, win, s0, s1, chunk = 0;
  const float* btab = nullptr;
  if (u < 128){ h = 0; win = u >> 3; chunk = u & 7; s0 = chunk*8; s1 = s0 + 8; }
  else { int uu = u - 128; h = 6 + (uu >> 4); win = uu & 15; s0 = 0; s1 = 4;
         btab = b256 + ((size_t)(h - 6) << 16); }
  const size_t hb = ((size_t)(b*8 + h)) << 18;

  char* pw = (char*)Pp[w];
  bf16x8 ones8;
  #pragma unroll
  for (int e = 0; e < 8; e++) ones8[e] = (short)0x3F80;    // bf16 1.0

  bf16x8 qf[2][2];
  #pragma unroll
  for (int mf = 0; mf < 2; mf++){
    int qt = w*32 + mf*16 + lr;
    int n = (h == 0) ? (win*256 + qt) : map16(win, qt);
    const unsigned short* qp = qb + hb + ((size_t)n << 6) + lg*8;
    qf[mf][0] = *(const bf16x8*)qp;
    qf[mf][1] = *(const bf16x8*)(qp + 32);
  }
  f32x4 ao[2][4] = {};
  f32x4 lsum4[2] = {};

  for (int s = s0; s < s1; s++){
    // QK^T: K fragments straight from global (d-contiguous 16B)
    f32x4 sv[2][4] = {};
    #pragma unroll
    for (int kt = 0; kt < 2; kt++){
      bf16x8 kf[4];
      #pragma unroll
      for (int nf = 0; nf < 4; nf++){
        int tk = s*64 + nf*16 + lr;
        int nk = (h == 0) ? tk : map16(win, tk);
        kf[nf] = *(const bf16x8*)(kb + hb + ((size_t)nk << 6) + kt*32 + lg*8);
      }
      #pragma unroll
      for (int mf = 0; mf < 2; mf++)
        #pragma unroll
        for (int nf = 0; nf < 4; nf++)
          sv[mf][nf] = MFMA(qf[mf][kt], kf[nf], sv[mf][nf]);
    }
    // scale + bias + exp (no shift), pack P -> wave-private LDS (swizzled)
    #pragma unroll
    for (int mf = 0; mf < 2; mf++)
      #pragma unroll
      for (int nf = 0; nf < 4; nf++)
        #pragma unroll
        for (int r = 0; r < 4; r++){
          float x = sv[mf][nf][r] * 0.125f;
          if (btab){
            int qw = w*32 + mf*16 + lg*4 + r;
            int kw = s*64 + nf*16 + lr;
            x += btab[(qw << 8) + kw];
          }
          float p = __expf(x);
          int row = mf*16 + lg*4 + r;
          int cb  = ((nf*16 + lr)*2) ^ ((row & 7) << 4);
          *(unsigned short*)(pw + row*128 + cb) = f2bf(p);
        }
    // PV: V^T fragments straight from global (n-contiguous 16B); lsum via ones-MFMA
    #pragma unroll
    for (int kg = 0; kg < 2; kg++){
      bf16x8 pa[2], vf[4];
      #pragma unroll
      for (int mf = 0; mf < 2; mf++){
        int row = mf*16 + lr;
        int cb  = (kg*64 + lg*16) ^ ((row & 7) << 4);
        pa[mf] = *(const bf16x8*)(pw + row*128 + cb);
      }
      int tv = s*64 + kg*32 + lg*8;
      int nv = (h == 0) ? tv : map16(win, tv);
      #pragma unroll
      for (int df = 0; df < 4; df++)
        vf[df] = *(const bf16x8*)(vtb + hb + ((size_t)(df*16 + lr) << 12) + nv);
      #pragma unroll
      for (int mf = 0; mf < 2; mf++){
        #pragma unroll
        for (int df = 0; df < 4; df++)
          ao[mf][df] = MFMA(pa[mf], vf[df], ao[mf][df]);
        lsum4[mf] = MFMA(pa[mf], ones8, lsum4[mf]);
      }
    }
  }

  if (h == 0){
    // pO row = (b*8 + chunk)*4096 + n, n = win*256 + qt
    #pragma unroll
    for (int mf = 0; mf < 2; mf++)
      #pragma unroll
      for (int r = 0; r < 4; r++){
        int qt = w*32 + mf*16 + lg*4 + r;
        size_t rowb = (((size_t)(b*8 + chunk)) << 12) + win*256 + qt;
        if (lr == 0) pl[rowb] = lsum4[mf][r];
        #pragma unroll
        for (int df = 0; df < 4; df++)
          pO[(rowb << 6) + df*16 + lr] = f2bf(ao[mf][df][r]);
      }
  } else {
    #pragma unroll
    for (int mf = 0; mf < 2; mf++)
      #pragma unroll
      for (int df = 0; df < 4; df++)
        #pragma unroll
        for (int r = 0; r < 4; r++){
          float o = ao[mf][df][r] / lsum4[mf][r];
          int qt = w*32 + mf*16 + lg*4 + r;
          int np = win*256 + qt;
          size_t base = (((size_t)b*4096 + np) << 10) + h*64 + df*16 + lr;
          unsigned short hi = f2bf(o);
          fsp[base] = hi;
          fsp[base + 512] = f2bf(o - bf2f(hi));
        }
  }
}

// ---------- combine head-0 KV chunks (plain sums) ----------
__global__ __launch_bounds__(256)
void k_comb(const unsigned short* __restrict__ pO, const float* __restrict__ pl,
            unsigned short* __restrict__ fsp){
  int tid = blockIdx.x*256 + threadIdx.x;      // 2M = 32768 rows * 64 d
  int d = tid & 63;
  int row = tid >> 6;
  int b = row >> 12;
  int n = row & 4095;
  float o = 0.f, L = 0.f;
  #pragma unroll
  for (int c = 0; c < 8; c++){
    size_t rr = (((size_t)(b*8 + c)) << 12) + n;
    L += pl[rr];
    o += bf2f(pO[(rr << 6) + d]);
  }
  o /= L;
  size_t base = (((size_t)b*4096 + n) << 10) + d;
  unsigned short hi = f2bf(o);
  fsp[base] = hi;
  fsp[base + 512] = f2bf(o - bf2f(hi));
}

// ---------- 64-token window attention (heads 1..5), validated ----------
__device__ __forceinline__ int mapw(int h, int u, int t){
  if (h <= 2) return (((u >> 2)*4 + (t >> 4)) << 6) + ((u & 3) << 4) + (t & 15);
  return (((u >> 3)*8 + (t >> 3)) << 6) + ((u & 7) << 3) + (t & 7);
}

__global__ __launch_bounds__(256, 2)
void k_win64(const unsigned short* __restrict__ qb, const unsigned short* __restrict__ kb,
             const unsigned short* __restrict__ vtb, const float* __restrict__ b64,
             unsigned short* __restrict__ fsp)
{
  __shared__ unsigned short KP[4][64*64];
  __shared__ unsigned short Vw[4][64*64];
  const int t = threadIdx.x, l = t & 63, w = t >> 6;
  const int lr = l & 15, lg = l >> 4;
  const int gid = blockIdx.x*4 + w;
  const int b = gid / 320;
  const int rem = gid % 320;
  const int h = 1 + (rem >> 6);
  const int u = rem & 63;
  const size_t hb = ((size_t)(b*8 + h)) << 18;

  #pragma unroll
  for (int i = 0; i < 8; i++){
    int row = i*8 + (l >> 3);
    int sc  = (((l & 7) ^ (row & 7)) << 3);
    gload16(kb  + hb + ((size_t)mapw(h,u,row) << 6) + sc, &KP[w][i*512]);
    gload16(vtb + hb + ((size_t)row << 12) + mapw(h,u,sc), &Vw[w][i*512]);
  }
  bf16x8 qf[4][2];
  #pragma unroll
  for (int mf = 0; mf < 4; mf++){
    int n = mapw(h, u, mf*16 + lr);
    const unsigned short* qp = qb + hb + ((size_t)n << 6) + lg*8;
    qf[mf][0] = *(const bf16x8*)qp;
    qf[mf][1] = *(const bf16x8*)(qp + 32);
  }
  __syncthreads();

  const char* kpc = (const char*)KP[w];
  const char* vwc = (const char*)Vw[w];
  f32x4 sv[4][4] = {};
  #pragma unroll
  for (int kt = 0; kt < 2; kt++){
    bf16x8 kf[4];
    #pragma unroll
    for (int nf = 0; nf < 4; nf++){
      int row = nf*16 + lr;
      int cb  = (kt*64 + lg*16) ^ ((row & 7) << 4);
      kf[nf] = *(const bf16x8*)(kpc + row*128 + cb);
    }
    #pragma unroll
    for (int mf = 0; mf < 4; mf++)
      #pragma unroll
      for (int nf = 0; nf < 4; nf++)
        sv[mf][nf] = MFMA(qf[mf][kt], kf[nf], sv[mf][nf]);
  }
  const float* bt = b64 + ((size_t)(h-1) << 12);
  float li[4][4];
  #pragma unroll
  for (int mf = 0; mf < 4; mf++)
    #pragma unroll
    for (int r = 0; r < 4; r++){
      int qt = mf*16 + lg*4 + r;
      #pragma unroll
      for (int nf = 0; nf < 4; nf++)
        sv[mf][nf][r] = sv[mf][nf][r]*0.125f + bt[(qt << 6) + nf*16 + lr];
      float mx = fmaxf(fmaxf(sv[mf][0][r], sv[mf][1][r]), fmaxf(sv[mf][2][r], sv[mf][3][r]));
      mx = fmaxf(mx, __shfl_xor(mx, 1));
      mx = fmaxf(mx, __shfl_xor(mx, 2));
      mx = fmaxf(mx, __shfl_xor(mx, 4));
      mx = fmaxf(mx, __shfl_xor(mx, 8));
      float rs = 0.f;
      #pragma unroll
      for (int nf = 0; nf < 4; nf++){
        float p = __expf(sv[mf][nf][r] - mx);
        sv[mf][nf][r] = p; rs += p;
      }
      rs += __shfl_xor(rs, 1); rs += __shfl_xor(rs, 2);
      rs += __shfl_xor(rs, 4); rs += __shfl_xor(rs, 8);
      li[mf][r] = rs;
    }
  char* pw = (char*)KP[w];
  #pragma unroll
  for (int mf = 0; mf < 4; mf++)
    #pragma unroll
    for (int nf = 0; nf < 4; nf++)
      #pragma unroll
      for (int r = 0; r < 4; r++){
        int row = mf*16 + lg*4 + r;
        int cb  = ((nf*16 + lr)*2) ^ ((row & 7) << 4);
        *(unsigned short*)(pw + row*128 + cb) = f2bf(sv[mf][nf][r]);
      }
  f32x4 ao[4][4] = {};
  #pragma unroll
  for (int kg = 0; kg < 2; kg++){
    bf16x8 pa[4], vf[4];
    #pragma unroll
    for (int mf = 0; mf < 4; mf++){
      int row = mf*16 + lr;
      int cb  = (kg*64 + lg*16) ^ ((row & 7) << 4);
      pa[mf] = *(const bf16x8*)(pw + row*128 + cb);
    }
    #pragma unroll
    for (int df = 0; df < 4; df++){
      int row = df*16 + lr;
      int cb  = (kg*64 + lg*16) ^ ((row & 7) << 4);
      vf[df] = *(const bf16x8*)(vwc + row*128 + cb);
    }
    #pragma unroll
    for (int mf = 0; mf < 4; mf++)
      #pragma unroll
      for (int df = 0; df < 4; df++)
        ao[mf][df] = MFMA(pa[mf], vf[df], ao[mf][df]);
  }
  #pragma unroll
  for (int mf = 0; mf < 4; mf++)
    #pragma unroll
    for (int df = 0; df < 4; df++)
      #pragma unroll
      for (int r = 0; r < 4; r++){
        float o = ao[mf][df][r] / li[mf][r];
        int qt = mf*16 + lg*4 + r;
        int np;
        if (h <= 2){
          int r4 = qt >> 4, w_ = (qt >> 2) & 3, c = qt & 3;
          np = (u >> 2)*256 + (u & 3)*64 + w_*16 + r4*4 + c;
        } else {
          np = u*64 + qt;
        }
        size_t base = (((size_t)b*4096 + np) << 10) + h*64 + df*16 + lr;
        unsigned short hi = f2bf(o);
        fsp[base] = hi;
        fsp[base + 512] = f2bf(o - bf2f(hi));
      }
}

// ---------- launch ----------
extern "C" void kernel_launch(void* const* d_in, const int* in_sizes, int n_in,
                              void* d_out, int out_size, void* d_ws, size_t ws_size,
                              hipStream_t stream) {
  const float* x     = (const float*)d_in[0];
  const float* Wq    = (const float*)d_in[1];
  const float* Wkv   = (const float*)d_in[2];
  const float* Wp    = (const float*)d_in[3];
  const float* bproj = (const float*)d_in[4];
  const float* t1 = (const float*)d_in[7];
  const float* t2 = (const float*)d_in[8];
  const float* t3 = (const float*)d_in[9];
  const float* t4 = (const float*)d_in[10];
  const float* t5 = (const float*)d_in[11];
  const float* t6 = (const float*)d_in[12];
  const float* t7 = (const float*)d_in[13];

  char* W = (char*)d_ws;
  size_t off = 0;
  auto alloc = [&](size_t bytes)->char*{
    char* p = W + off; off += (bytes + 255) & ~(size_t)255; return p;
  };
  unsigned short* xb   = (unsigned short*)alloc((size_t)32768*512*2);   // dead after gemm0
  unsigned short* wqkv = (unsigned short*)alloc((size_t)1536*512*2);    // dead after gemm0
  unsigned short* wsp2 = (unsigned short*)alloc((size_t)512*2048*2);
  unsigned short* qbuf = (unsigned short*)alloc((size_t)8*8*4096*64*2);
  unsigned short* kbuf = (unsigned short*)alloc((size_t)8*8*4096*64*2);
  unsigned short* vtb  = (unsigned short*)alloc((size_t)8*8*4096*64*2);
  unsigned short* fsp  = (unsigned short*)alloc((size_t)32768*1024*2);
  float* b64  = (float*)alloc((size_t)5*64*64*4);
  float* b256 = (float*)alloc((size_t)2*256*256*4);
  if (off > ws_size) return;

  // head-0 partials alias dead regions (flash runs after gemm0):
  unsigned short* pO = xb;                 // (8b*8c)*4096 rows * 64 d * 2B = 32 MiB
  float* pl = (float*)wqkv;                // 64*4096*4B = 1 MiB

  k_conv_x<<<8192, 256, 0, stream>>>(x, xb, 32768*512);
  k_conv_w<<<640, 256, 0, stream>>>(Wq, Wkv, Wp, wqkv, wsp2);
  k_bias<<<64, 256, 0, stream>>>(t1,t2,t3,t4,t5,t6,t7, b64, b256);

  k_gemm<0><<<3072, 256, 0, stream>>>(xb, wqkv, 32768,
                                      qbuf, kbuf, vtb, nullptr, nullptr);
  k_flash<<<1280, 512, 0, stream>>>(qbuf, kbuf, vtb, b256, fsp, pO, pl);
  k_comb<<<8192, 256, 0, stream>>>(pO, pl, fsp);
  k_win64<<<640, 256, 0, stream>>>(qbuf, kbuf, vtb, b64, fsp);
  k_gemm<1><<<1024, 256, 0, stream>>>(fsp, wsp2, 32768,
                                      nullptr, nullptr, nullptr, (float*)d_out, bproj);
}

// Round 11
// 360.778 us; speedup vs baseline: 1.7954x; 1.1152x over previous
//
#include <hip/hip_runtime.h>
#include <stdint.h>

typedef __attribute__((ext_vector_type(8))) short bf16x8;
typedef __attribute__((ext_vector_type(4))) float f32x4;

__device__ __forceinline__ unsigned short f2bf(float f){
  union { float f; unsigned u; } v; v.f = f;
  return (unsigned short)((v.u + 0x7fffu + ((v.u >> 16) & 1u)) >> 16);
}
__device__ __forceinline__ float bf2f(unsigned short h){
  union { unsigned u; float f; } v; v.u = ((unsigned)h) << 16; return v.f;
}
__device__ __forceinline__ void gload16(const void* g, void* lds){
  __builtin_amdgcn_global_load_lds((const __attribute__((address_space(1))) unsigned int*)g,
                                   (__attribute__((address_space(3))) unsigned int*)lds,
                                   16, 0, 0);
}
#define MFMA(a,b,c) __builtin_amdgcn_mfma_f32_16x16x32_bf16((a),(b),(c),0,0,0)

// B=8, H=W=64, N=4096, C=512, nh=8, hd=64

__global__ void k_conv_x(const float* __restrict__ x, unsigned short* __restrict__ xb, int n){
  int i = (blockIdx.x*256 + threadIdx.x)*8;
  if (i >= n) return;
  float4 a = *(const float4*)(x+i);
  float4 b = *(const float4*)(x+i+4);
  *(ushort4*)(xb+i)   = make_ushort4(f2bf(a.x), f2bf(a.y), f2bf(a.z), f2bf(a.w));
  *(ushort4*)(xb+i+4) = make_ushort4(f2bf(b.x), f2bf(b.y), f2bf(b.z), f2bf(b.w));
}

// wqkv[1536][512] bf16; wsp[512][512] bf16 = bf16(Wproj)
__global__ void k_conv_w(const float* __restrict__ Wq, const float* __restrict__ Wkv,
                         const float* __restrict__ Wp,
                         unsigned short* __restrict__ wqkv, unsigned short* __restrict__ wsp){
  int i = blockIdx.x*256 + threadIdx.x;
  int stride = gridDim.x*256;
  for (int e = i; e < 1536*512; e += stride){
    int r = e >> 9;
    wqkv[e] = f2bf(r < 512 ? Wq[e] : Wkv[e - 512*512]);
  }
  for (int e = i; e < 512*512; e += stride)
    wsp[e] = f2bf(Wp[e]);
}

// bias64: heads 1..5 (p=4 strip-grouped-with-mask, p=8). bias256: heads 6,7 (p=16).
__global__ void k_bias(const float* t1,const float* t2,const float* t3,const float* t4,
                       const float* t5,const float* t6,const float* t7,
                       float* __restrict__ b64, float* __restrict__ b256){
  int i = blockIdx.x*256 + threadIdx.x;
  int stride = gridDim.x*256;
  for (int e = i; e < 5*4096; e += stride){
    int hh = e >> 12;
    int q = (e >> 6) & 63, kk = e & 63;
    float v;
    if (hh < 2){
      const float* tb = hh ? t2 : t1;
      int r1=q>>4, i1=(q>>2)&3, c1=q&3;
      int r2=kk>>4, i2=(kk>>2)&3, c2=kk&3;
      v = (i1==i2) ? tb[(r1-r2+3)*7 + (c1-c2+3)] : -1e30f;
    } else {
      const float* tb = (hh==2)?t3:((hh==3)?t4:t5);
      int r1=q>>3, c1=q&7, r2=kk>>3, c2=kk&7;
      v = tb[(r1-r2+7)*15 + (c1-c2+7)];
    }
    b64[e] = v;
  }
  for (int e = i; e < 2*65536; e += stride){
    int hh = e >> 16; int q = (e >> 8) & 255, kk = e & 255;
    const float* tb = hh ? t7 : t6;
    int r1=q>>4, c1=q&15, r2=kk>>4, c2=kk&15;
    b256[e] = tb[(r1-r2+15)*31 + (c1-c2+15)];
  }
}

// ---------- GEMM (validated), K=512 for both uses ----------
// EPI 0: A=xb[32768][512], B=wqkv[1536][512] -> scatter q/k + v^T.
// EPI 1: A=fsp[32768][512], B=wsp[512][512] -> f32 + bias to out.
template<int EPI>
__global__ __launch_bounds__(256, 2)
void k_gemm(const unsigned short* __restrict__ A, const unsigned short* __restrict__ Bw,
            int M,
            unsigned short* __restrict__ oq, unsigned short* __restrict__ ok,
            unsigned short* __restrict__ ovt,
            float* __restrict__ of, const float* __restrict__ bias)
{
  __shared__ unsigned short As[128*64];
  __shared__ unsigned short Bs[128*64];
  const int t = threadIdx.x, l = t & 63, w = t >> 6;
  const int mt = M >> 7;
  const int bm = blockIdx.x % mt, bn = blockIdx.x / mt;
  const int m0 = bm << 7, n0 = bn << 7;
  const int wr = w >> 1, wc = w & 1;
  const int lr = l & 15, lg = l >> 4;
  f32x4 acc[4][4] = {};

  for (int k0 = 0; k0 < 512; k0 += 64){
    #pragma unroll
    for (int i = 0; i < 4; i++){
      int rowb = i*32 + w*8;
      int row  = rowb + (l >> 3);
      int sc   = (((l & 7) ^ (row & 7)) << 3);
      gload16(A  + (size_t)(m0 + row)*512 + k0 + sc, &As[rowb*64]);
      gload16(Bw + (size_t)(n0 + row)*512 + k0 + sc, &Bs[rowb*64]);
    }
    __syncthreads();
    #pragma unroll
    for (int kt = 0; kt < 2; kt++){
      bf16x8 af[4], bfr[4];
      #pragma unroll
      for (int mi = 0; mi < 4; mi++){
        int row = wr*64 + mi*16 + lr;
        int cb  = (kt*64 + lg*16) ^ ((row & 7) << 4);
        af[mi] = *(const bf16x8*)((const char*)As + row*128 + cb);
      }
      #pragma unroll
      for (int ni = 0; ni < 4; ni++){
        int row = wc*64 + ni*16 + lr;
        int cb  = (kt*64 + lg*16) ^ ((row & 7) << 4);
        bfr[ni] = *(const bf16x8*)((const char*)Bs + row*128 + cb);
      }
      #pragma unroll
      for (int mi = 0; mi < 4; mi++)
        #pragma unroll
        for (int ni = 0; ni < 4; ni++)
          acc[mi][ni] = MFMA(af[mi], bfr[ni], acc[mi][ni]);
    }
    __syncthreads();
  }

  #pragma unroll
  for (int mi = 0; mi < 4; mi++){
    #pragma unroll
    for (int ni = 0; ni < 4; ni++){
      int m = m0 + wr*64 + mi*16 + lg*4;
      int o = n0 + wc*64 + ni*16 + lr;
      if (EPI == 0){
        int which = o >> 9, oo = o & 511, h = oo >> 6, d = oo & 63;
        int b_ = m >> 12, n_ = m & 4095;
        if (which == 2){
          *(ushort4*)(ovt + ((((size_t)b_*8 + h)*64 + d) << 12) + n_) =
            make_ushort4(f2bf(acc[mi][ni][0]), f2bf(acc[mi][ni][1]),
                         f2bf(acc[mi][ni][2]), f2bf(acc[mi][ni][3]));
        } else {
          unsigned short* dst = (which == 0) ? oq : ok;
          size_t base = (((size_t)(b_*8 + h)) << 18) + ((size_t)n_ << 6) + d;
          #pragma unroll
          for (int r = 0; r < 4; r++)
            dst[base + (size_t)r*64] = f2bf(acc[mi][ni][r]);
        }
      } else {
        float bv = bias[o];
        #pragma unroll
        for (int r = 0; r < 4; r++)
          of[(size_t)(m + r)*512 + o] = acc[mi][ni][r] + bv;
      }
    }
  }
}

// ---------- flash: 8 independent waves/block, register-direct K/V + K-prefetch ----------
__device__ __forceinline__ int map16(int win, int t){
  return (((win >> 2)*16 + (t >> 4)) << 6) + ((win & 3) << 4) + (t & 15);
}

__global__ __launch_bounds__(512)
void k_flash(const unsigned short* __restrict__ qb, const unsigned short* __restrict__ kb,
             const unsigned short* __restrict__ vtb, const float* __restrict__ b256,
             unsigned short* __restrict__ fsp,
             unsigned short* __restrict__ pO, float* __restrict__ pl)
{
  __shared__ unsigned short Pp[8][2048];           // per-wave P: 32x64 bf16
  const int t = threadIdx.x, l = t & 63, w = t >> 6;
  const int lr = l & 15, lg = l >> 4;
  const int v = (blockIdx.x & 7)*160 + (blockIdx.x >> 3);   // XCD-pinned, 1280 blocks
  const int b = v / 160, u = v % 160;
  int h, win, s0, s1, chunk = 0;
  const float* btab = nullptr;
  if (u < 128){ h = 0; win = u >> 3; chunk = u & 7; s0 = chunk*8; s1 = s0 + 8; }
  else { int uu = u - 128; h = 6 + (uu >> 4); win = uu & 15; s0 = 0; s1 = 4;
         btab = b256 + ((size_t)(h - 6) << 16); }
  const size_t hb = ((size_t)(b*8 + h)) << 18;

  char* pw = (char*)Pp[w];
  bf16x8 ones8;
  #pragma unroll
  for (int e = 0; e < 8; e++) ones8[e] = (short)0x3F80;    // bf16 1.0

  bf16x8 qf[2][2];
  #pragma unroll
  for (int mf = 0; mf < 2; mf++){
    int qt = w*32 + mf*16 + lr;
    int n = (h == 0) ? (win*256 + qt) : map16(win, qt);
    const unsigned short* qp = qb + hb + ((size_t)n << 6) + lg*8;
    qf[mf][0] = *(const bf16x8*)qp;
    qf[mf][1] = *(const bf16x8*)(qp + 32);
  }
  f32x4 ao[2][4] = {};
  f32x4 lsum4[2] = {};

  auto loadK = [&](int s, bf16x8 (&kf)[2][4]){
    #pragma unroll
    for (int kt = 0; kt < 2; kt++)
      #pragma unroll
      for (int nf = 0; nf < 4; nf++){
        int tk = s*64 + nf*16 + lr;
        int nk = (h == 0) ? tk : map16(win, tk);
        kf[kt][nf] = *(const bf16x8*)(kb + hb + ((size_t)nk << 6) + kt*32 + lg*8);
      }
  };

  auto STEP = [&](int s, bf16x8 (&kf)[2][4], int ps, bf16x8 (&pkf)[2][4], bool doPref){
    // QK^T
    f32x4 sv[2][4] = {};
    #pragma unroll
    for (int kt = 0; kt < 2; kt++)
      #pragma unroll
      for (int mf = 0; mf < 2; mf++)
        #pragma unroll
        for (int nf = 0; nf < 4; nf++)
          sv[mf][nf] = MFMA(qf[mf][kt], kf[kt][nf], sv[mf][nf]);
    // scale (+bias) + exp, pack P -> wave-private LDS (swizzled)
    #pragma unroll
    for (int mf = 0; mf < 2; mf++)
      #pragma unroll
      for (int nf = 0; nf < 4; nf++)
        #pragma unroll
        for (int r = 0; r < 4; r++){
          float x = sv[mf][nf][r] * 0.125f;
          if (btab){
            int qw = w*32 + mf*16 + lg*4 + r;
            int kw = s*64 + nf*16 + lr;
            x += btab[(qw << 8) + kw];
          }
          float p = __expf(x);
          int row = mf*16 + lg*4 + r;
          int cb  = ((nf*16 + lr)*2) ^ ((row & 7) << 4);
          *(unsigned short*)(pw + row*128 + cb) = f2bf(p);
        }
    // V fragment loads (both halves) — latency hidden under K-prefetch + P ds_reads
    bf16x8 vf[2][4];
    #pragma unroll
    for (int kg = 0; kg < 2; kg++){
      int tv = s*64 + kg*32 + lg*8;
      int nv = (h == 0) ? tv : map16(win, tv);
      #pragma unroll
      for (int df = 0; df < 4; df++)
        vf[kg][df] = *(const bf16x8*)(vtb + hb + ((size_t)(df*16 + lr) << 12) + nv);
    }
    // prefetch next step's K fragments (covered by PV)
    if (doPref) loadK(ps, pkf);
    // PV + lsum via ones-MFMA
    #pragma unroll
    for (int kg = 0; kg < 2; kg++){
      bf16x8 pa[2];
      #pragma unroll
      for (int mf = 0; mf < 2; mf++){
        int row = mf*16 + lr;
        int cb  = (kg*64 + lg*16) ^ ((row & 7) << 4);
        pa[mf] = *(const bf16x8*)(pw + row*128 + cb);
      }
      #pragma unroll
      for (int mf = 0; mf < 2; mf++){
        #pragma unroll
        for (int df = 0; df < 4; df++)
          ao[mf][df] = MFMA(pa[mf], vf[kg][df], ao[mf][df]);
        lsum4[mf] = MFMA(pa[mf], ones8, lsum4[mf]);
      }
    }
  };

  bf16x8 kfA[2][4], kfB[2][4];
  loadK(s0, kfA);
  const int np = (s1 - s0) >> 1;
  for (int sp = 0; sp < np; sp++){
    int s = s0 + sp*2;
    STEP(s,     kfA, s+1, kfB, true);
    STEP(s+1,   kfB, s+2, kfA, sp + 1 < np);
  }

  if (h == 0){
    #pragma unroll
    for (int mf = 0; mf < 2; mf++)
      #pragma unroll
      for (int r = 0; r < 4; r++){
        int qt = w*32 + mf*16 + lg*4 + r;
        size_t rowb = (((size_t)(b*8 + chunk)) << 12) + win*256 + qt;
        if (lr == 0) pl[rowb] = lsum4[mf][r];
        #pragma unroll
        for (int df = 0; df < 4; df++)
          pO[(rowb << 6) + df*16 + lr] = f2bf(ao[mf][df][r]);
      }
  } else {
    #pragma unroll
    for (int mf = 0; mf < 2; mf++)
      #pragma unroll
      for (int df = 0; df < 4; df++)
        #pragma unroll
        for (int r = 0; r < 4; r++){
          float o = ao[mf][df][r] / lsum4[mf][r];
          int qt = w*32 + mf*16 + lg*4 + r;
          int np2 = win*256 + qt;
          size_t base = (((size_t)b*4096 + np2) << 9) + h*64 + df*16 + lr;
          fsp[base] = f2bf(o);
        }
  }
}

// ---------- combine head-0 KV chunks (plain sums) ----------
__global__ __launch_bounds__(256)
void k_comb(const unsigned short* __restrict__ pO, const float* __restrict__ pl,
            unsigned short* __restrict__ fsp){
  int tid = blockIdx.x*256 + threadIdx.x;      // 2M = 32768 rows * 64 d
  int d = tid & 63;
  int row = tid >> 6;
  int b = row >> 12;
  int n = row & 4095;
  float o = 0.f, L = 0.f;
  #pragma unroll
  for (int c = 0; c < 8; c++){
    size_t rr = (((size_t)(b*8 + c)) << 12) + n;
    L += pl[rr];
    o += bf2f(pO[(rr << 6) + d]);
  }
  o /= L;
  fsp[(((size_t)b*4096 + n) << 9) + d] = f2bf(o);
}

// ---------- 64-token window attention (heads 1..5), validated ----------
__device__ __forceinline__ int mapw(int h, int u, int t){
  if (h <= 2) return (((u >> 2)*4 + (t >> 4)) << 6) + ((u & 3) << 4) + (t & 15);
  return (((u >> 3)*8 + (t >> 3)) << 6) + ((u & 7) << 3) + (t & 7);
}

__global__ __launch_bounds__(256, 2)
void k_win64(const unsigned short* __restrict__ qb, const unsigned short* __restrict__ kb,
             const unsigned short* __restrict__ vtb, const float* __restrict__ b64,
             unsigned short* __restrict__ fsp)
{
  __shared__ unsigned short KP[4][64*64];
  __shared__ unsigned short Vw[4][64*64];
  const int t = threadIdx.x, l = t & 63, w = t >> 6;
  const int lr = l & 15, lg = l >> 4;
  const int gid = blockIdx.x*4 + w;
  const int b = gid / 320;
  const int rem = gid % 320;
  const int h = 1 + (rem >> 6);
  const int u = rem & 63;
  const size_t hb = ((size_t)(b*8 + h)) << 18;

  #pragma unroll
  for (int i = 0; i < 8; i++){
    int row = i*8 + (l >> 3);
    int sc  = (((l & 7) ^ (row & 7)) << 3);
    gload16(kb  + hb + ((size_t)mapw(h,u,row) << 6) + sc, &KP[w][i*512]);
    gload16(vtb + hb + ((size_t)row << 12) + mapw(h,u,sc), &Vw[w][i*512]);
  }
  bf16x8 qf[4][2];
  #pragma unroll
  for (int mf = 0; mf < 4; mf++){
    int n = mapw(h, u, mf*16 + lr);
    const unsigned short* qp = qb + hb + ((size_t)n << 6) + lg*8;
    qf[mf][0] = *(const bf16x8*)qp;
    qf[mf][1] = *(const bf16x8*)(qp + 32);
  }
  __syncthreads();

  const char* kpc = (const char*)KP[w];
  const char* vwc = (const char*)Vw[w];
  f32x4 sv[4][4] = {};
  #pragma unroll
  for (int kt = 0; kt < 2; kt++){
    bf16x8 kf[4];
    #pragma unroll
    for (int nf = 0; nf < 4; nf++){
      int row = nf*16 + lr;
      int cb  = (kt*64 + lg*16) ^ ((row & 7) << 4);
      kf[nf] = *(const bf16x8*)(kpc + row*128 + cb);
    }
    #pragma unroll
    for (int mf = 0; mf < 4; mf++)
      #pragma unroll
      for (int nf = 0; nf < 4; nf++)
        sv[mf][nf] = MFMA(qf[mf][kt], kf[nf], sv[mf][nf]);
  }
  const float* bt = b64 + ((size_t)(h-1) << 12);
  float li[4][4];
  #pragma unroll
  for (int mf = 0; mf < 4; mf++)
    #pragma unroll
    for (int r = 0; r < 4; r++){
      int qt = mf*16 + lg*4 + r;
      #pragma unroll
      for (int nf = 0; nf < 4; nf++)
        sv[mf][nf][r] = sv[mf][nf][r]*0.125f + bt[(qt << 6) + nf*16 + lr];
      float mx = fmaxf(fmaxf(sv[mf][0][r], sv[mf][1][r]), fmaxf(sv[mf][2][r], sv[mf][3][r]));
      mx = fmaxf(mx, __shfl_xor(mx, 1));
      mx = fmaxf(mx, __shfl_xor(mx, 2));
      mx = fmaxf(mx, __shfl_xor(mx, 4));
      mx = fmaxf(mx, __shfl_xor(mx, 8));
      float rs = 0.f;
      #pragma unroll
      for (int nf = 0; nf < 4; nf++){
        float p = __expf(sv[mf][nf][r] - mx);
        sv[mf][nf][r] = p; rs += p;
      }
      rs += __shfl_xor(rs, 1); rs += __shfl_xor(rs, 2);
      rs += __shfl_xor(rs, 4); rs += __shfl_xor(rs, 8);
      li[mf][r] = rs;
    }
  char* pw = (char*)KP[w];
  #pragma unroll
  for (int mf = 0; mf < 4; mf++)
    #pragma unroll
    for (int nf = 0; nf < 4; nf++)
      #pragma unroll
      for (int r = 0; r < 4; r++){
        int row = mf*16 + lg*4 + r;
        int cb  = ((nf*16 + lr)*2) ^ ((row & 7) << 4);
        *(unsigned short*)(pw + row*128 + cb) = f2bf(sv[mf][nf][r]);
      }
  f32x4 ao[4][4] = {};
  #pragma unroll
  for (int kg = 0; kg < 2; kg++){
    bf16x8 pa[4], vf[4];
    #pragma unroll
    for (int mf = 0; mf < 4; mf++){
      int row = mf*16 + lr;
      int cb  = (kg*64 + lg*16) ^ ((row & 7) << 4);
      pa[mf] = *(const bf16x8*)(pw + row*128 + cb);
    }
    #pragma unroll
    for (int df = 0; df < 4; df++){
      int row = df*16 + lr;
      int cb  = (kg*64 + lg*16) ^ ((row & 7) << 4);
      vf[df] = *(const bf16x8*)(vwc + row*128 + cb);
    }
    #pragma unroll
    for (int mf = 0; mf < 4; mf++)
      #pragma unroll
      for (int df = 0; df < 4; df++)
        ao[mf][df] = MFMA(pa[mf], vf[df], ao[mf][df]);
  }
  #pragma unroll
  for (int mf = 0; mf < 4; mf++)
    #pragma unroll
    for (int df = 0; df < 4; df++)
      #pragma unroll
      for (int r = 0; r < 4; r++){
        float o = ao[mf][df][r] / li[mf][r];
        int qt = mf*16 + lg*4 + r;
        int np;
        if (h <= 2){
          int r4 = qt >> 4, w_ = (qt >> 2) & 3, c = qt & 3;
          np = (u >> 2)*256 + (u & 3)*64 + w_*16 + r4*4 + c;
        } else {
          np = u*64 + qt;
        }
        fsp[(((size_t)b*4096 + np) << 9) + h*64 + df*16 + lr] = f2bf(o);
      }
}

// ---------- launch ----------
extern "C" void kernel_launch(void* const* d_in, const int* in_sizes, int n_in,
                              void* d_out, int out_size, void* d_ws, size_t ws_size,
                              hipStream_t stream) {
  const float* x     = (const float*)d_in[0];
  const float* Wq    = (const float*)d_in[1];
  const float* Wkv   = (const float*)d_in[2];
  const float* Wp    = (const float*)d_in[3];
  const float* bproj = (const float*)d_in[4];
  const float* t1 = (const float*)d_in[7];
  const float* t2 = (const float*)d_in[8];
  const float* t3 = (const float*)d_in[9];
  const float* t4 = (const float*)d_in[10];
  const float* t5 = (const float*)d_in[11];
  const float* t6 = (const float*)d_in[12];
  const float* t7 = (const float*)d_in[13];

  char* W = (char*)d_ws;
  size_t off = 0;
  auto alloc = [&](size_t bytes)->char*{
    char* p = W + off; off += (bytes + 255) & ~(size_t)255; return p;
  };
  unsigned short* xb   = (unsigned short*)alloc((size_t)32768*512*2);   // dead after gemm0
  unsigned short* wqkv = (unsigned short*)alloc((size_t)1536*512*2);    // dead after gemm0
  unsigned short* wsp  = (unsigned short*)alloc((size_t)512*512*2);
  unsigned short* qbuf = (unsigned short*)alloc((size_t)8*8*4096*64*2);
  unsigned short* kbuf = (unsigned short*)alloc((size_t)8*8*4096*64*2);
  unsigned short* vtb  = (unsigned short*)alloc((size_t)8*8*4096*64*2);
  unsigned short* fsp  = (unsigned short*)alloc((size_t)32768*512*2);
  float* b64  = (float*)alloc((size_t)5*64*64*4);
  float* b256 = (float*)alloc((size_t)2*256*256*4);
  if (off > ws_size) return;

  // head-0 partials alias dead regions (flash runs after gemm0):
  unsigned short* pO = xb;                 // (8b*8c)*4096 rows * 64 d * 2B = 32 MiB
  float* pl = (float*)wqkv;                // 64*4096*4B = 1 MiB

  k_conv_x<<<8192, 256, 0, stream>>>(x, xb, 32768*512);
  k_conv_w<<<640, 256, 0, stream>>>(Wq, Wkv, Wp, wqkv, wsp);
  k_bias<<<64, 256, 0, stream>>>(t1,t2,t3,t4,t5,t6,t7, b64, b256);

  k_gemm<0><<<3072, 256, 0, stream>>>(xb, wqkv, 32768,
                                      qbuf, kbuf, vtb, nullptr, nullptr);
  k_flash<<<1280, 512, 0, stream>>>(qbuf, kbuf, vtb, b256, fsp, pO, pl);
  k_comb<<<8192, 256, 0, stream>>>(pO, pl, fsp);
  k_win64<<<640, 256, 0, stream>>>(qbuf, kbuf, vtb, b64, fsp);
  k_gemm<1><<<1024, 256, 0, stream>>>(fsp, wsp, 32768,
                                      nullptr, nullptr, nullptr, (float*)d_out, bproj);
}

// Round 12
// 341.711 us; speedup vs baseline: 1.8956x; 1.0558x over previous
//
#include <hip/hip_runtime.h>
#include <stdint.h>

typedef __attribute__((ext_vector_type(8))) short bf16x8;
typedef __attribute__((ext_vector_type(4))) float f32x4;

#define LOG2E 1.4426950408889634f

__device__ __forceinline__ unsigned short f2bf(float f){
  union { float f; unsigned u; } v; v.f = f;
  return (unsigned short)((v.u + 0x7fffu + ((v.u >> 16) & 1u)) >> 16);
}
__device__ __forceinline__ float bf2f(unsigned short h){
  union { unsigned u; float f; } v; v.u = ((unsigned)h) << 16; return v.f;
}
__device__ __forceinline__ float fast_exp2(float x){
  float r; asm("v_exp_f32 %0, %1" : "=v"(r) : "v"(x)); return r;
}
__device__ __forceinline__ unsigned cvt_pk_bf16(float lo, float hi){
  unsigned r; asm("v_cvt_pk_bf16_f32 %0, %1, %2" : "=v"(r) : "v"(lo), "v"(hi)); return r;
}
__device__ __forceinline__ void gload16(const void* g, void* lds){
  __builtin_amdgcn_global_load_lds((const __attribute__((address_space(1))) unsigned int*)g,
                                   (__attribute__((address_space(3))) unsigned int*)lds,
                                   16, 0, 0);
}
#define MFMA(a,b,c) __builtin_amdgcn_mfma_f32_16x16x32_bf16((a),(b),(c),0,0,0)

// B=8, H=W=64, N=4096, C=512, nh=8, hd=64

__global__ void k_conv_x(const float* __restrict__ x, unsigned short* __restrict__ xb, int n){
  int i = (blockIdx.x*256 + threadIdx.x)*8;
  if (i >= n) return;
  float4 a = *(const float4*)(x+i);
  float4 b = *(const float4*)(x+i+4);
  *(ushort4*)(xb+i)   = make_ushort4(f2bf(a.x), f2bf(a.y), f2bf(a.z), f2bf(a.w));
  *(ushort4*)(xb+i+4) = make_ushort4(f2bf(b.x), f2bf(b.y), f2bf(b.z), f2bf(b.w));
}

// wqkv[1536][512] bf16; wsp[512][512] bf16 = bf16(Wproj)
__global__ void k_conv_w(const float* __restrict__ Wq, const float* __restrict__ Wkv,
                         const float* __restrict__ Wp,
                         unsigned short* __restrict__ wqkv, unsigned short* __restrict__ wsp){
  int i = blockIdx.x*256 + threadIdx.x;
  int stride = gridDim.x*256;
  for (int e = i; e < 1536*512; e += stride){
    int r = e >> 9;
    wqkv[e] = f2bf(r < 512 ? Wq[e] : Wkv[e - 512*512]);
  }
  for (int e = i; e < 512*512; e += stride)
    wsp[e] = f2bf(Wp[e]);
}

// Bias tables PRE-SCALED by log2(e): softmax runs in base-2 (v_exp_f32 = 2^x).
__global__ void k_bias(const float* t1,const float* t2,const float* t3,const float* t4,
                       const float* t5,const float* t6,const float* t7,
                       float* __restrict__ b64, float* __restrict__ b256){
  int i = blockIdx.x*256 + threadIdx.x;
  int stride = gridDim.x*256;
  for (int e = i; e < 5*4096; e += stride){
    int hh = e >> 12;
    int q = (e >> 6) & 63, kk = e & 63;
    float v;
    if (hh < 2){
      const float* tb = hh ? t2 : t1;
      int r1=q>>4, i1=(q>>2)&3, c1=q&3;
      int r2=kk>>4, i2=(kk>>2)&3, c2=kk&3;
      v = (i1==i2) ? tb[(r1-r2+3)*7 + (c1-c2+3)] : -1e30f;
    } else {
      const float* tb = (hh==2)?t3:((hh==3)?t4:t5);
      int r1=q>>3, c1=q&7, r2=kk>>3, c2=kk&7;
      v = tb[(r1-r2+7)*15 + (c1-c2+7)];
    }
    b64[e] = v * LOG2E;
  }
  for (int e = i; e < 2*65536; e += stride){
    int hh = e >> 16; int q = (e >> 8) & 255, kk = e & 255;
    const float* tb = hh ? t7 : t6;
    int r1=q>>4, c1=q&15, r2=kk>>4, c2=kk&15;
    b256[e] = tb[(r1-r2+15)*31 + (c1-c2+15)] * LOG2E;
  }
}

// ---------- GEMM (validated), K=512 for both uses ----------
template<int EPI>
__global__ __launch_bounds__(256, 2)
void k_gemm(const unsigned short* __restrict__ A, const unsigned short* __restrict__ Bw,
            int M,
            unsigned short* __restrict__ oq, unsigned short* __restrict__ ok,
            unsigned short* __restrict__ ovt,
            float* __restrict__ of, const float* __restrict__ bias)
{
  __shared__ unsigned short As[128*64];
  __shared__ unsigned short Bs[128*64];
  const int t = threadIdx.x, l = t & 63, w = t >> 6;
  const int mt = M >> 7;
  const int bm = blockIdx.x % mt, bn = blockIdx.x / mt;
  const int m0 = bm << 7, n0 = bn << 7;
  const int wr = w >> 1, wc = w & 1;
  const int lr = l & 15, lg = l >> 4;
  f32x4 acc[4][4] = {};

  for (int k0 = 0; k0 < 512; k0 += 64){
    #pragma unroll
    for (int i = 0; i < 4; i++){
      int rowb = i*32 + w*8;
      int row  = rowb + (l >> 3);
      int sc   = (((l & 7) ^ (row & 7)) << 3);
      gload16(A  + (size_t)(m0 + row)*512 + k0 + sc, &As[rowb*64]);
      gload16(Bw + (size_t)(n0 + row)*512 + k0 + sc, &Bs[rowb*64]);
    }
    __syncthreads();
    #pragma unroll
    for (int kt = 0; kt < 2; kt++){
      bf16x8 af[4], bfr[4];
      #pragma unroll
      for (int mi = 0; mi < 4; mi++){
        int row = wr*64 + mi*16 + lr;
        int cb  = (kt*64 + lg*16) ^ ((row & 7) << 4);
        af[mi] = *(const bf16x8*)((const char*)As + row*128 + cb);
      }
      #pragma unroll
      for (int ni = 0; ni < 4; ni++){
        int row = wc*64 + ni*16 + lr;
        int cb  = (kt*64 + lg*16) ^ ((row & 7) << 4);
        bfr[ni] = *(const bf16x8*)((const char*)Bs + row*128 + cb);
      }
      #pragma unroll
      for (int mi = 0; mi < 4; mi++)
        #pragma unroll
        for (int ni = 0; ni < 4; ni++)
          acc[mi][ni] = MFMA(af[mi], bfr[ni], acc[mi][ni]);
    }
    __syncthreads();
  }

  #pragma unroll
  for (int mi = 0; mi < 4; mi++){
    #pragma unroll
    for (int ni = 0; ni < 4; ni++){
      int m = m0 + wr*64 + mi*16 + lg*4;
      int o = n0 + wc*64 + ni*16 + lr;
      if (EPI == 0){
        int which = o >> 9, oo = o & 511, h = oo >> 6, d = oo & 63;
        int b_ = m >> 12, n_ = m & 4095;
        if (which == 2){
          *(ushort4*)(ovt + ((((size_t)b_*8 + h)*64 + d) << 12) + n_) =
            make_ushort4(f2bf(acc[mi][ni][0]), f2bf(acc[mi][ni][1]),
                         f2bf(acc[mi][ni][2]), f2bf(acc[mi][ni][3]));
        } else {
          unsigned short* dst = (which == 0) ? oq : ok;
          size_t base = (((size_t)(b_*8 + h)) << 18) + ((size_t)n_ << 6) + d;
          #pragma unroll
          for (int r = 0; r < 4; r++)
            dst[base + (size_t)r*64] = f2bf(acc[mi][ni][r]);
        }
      } else {
        float bv = bias[o];
        #pragma unroll
        for (int r = 0; r < 4; r++)
          of[(size_t)(m + r)*512 + o] = acc[mi][ni][r] + bv;
      }
    }
  }
}

// ---------- flash: 8 independent waves/block, register-direct K/V (R10 structure) ----------
// Softmax in base-2 (pre-scaled bias, raw v_exp_f32); P pack via v_cvt_pk_bf16_f32.
__device__ __forceinline__ int map16(int win, int t){
  return (((win >> 2)*16 + (t >> 4)) << 6) + ((win & 3) << 4) + (t & 15);
}

__global__ __launch_bounds__(512)
void k_flash(const unsigned short* __restrict__ qb, const unsigned short* __restrict__ kb,
             const unsigned short* __restrict__ vtb, const float* __restrict__ b256,
             unsigned short* __restrict__ fsp,
             unsigned short* __restrict__ pO, float* __restrict__ pl)
{
  __shared__ unsigned short Pp[8][2048];           // per-wave P: 32x64 bf16
  const int t = threadIdx.x, l = t & 63, w = t >> 6;
  const int lr = l & 15, lg = l >> 4;
  const int v = (blockIdx.x & 7)*160 + (blockIdx.x >> 3);   // XCD-pinned, 1280 blocks
  const int b = v / 160, u = v % 160;
  int h, win, s0, s1, chunk = 0;
  const float* btab = nullptr;
  if (u < 128){ h = 0; win = u >> 3; chunk = u & 7; s0 = chunk*8; s1 = s0 + 8; }
  else { int uu = u - 128; h = 6 + (uu >> 4); win = uu & 15; s0 = 0; s1 = 4;
         btab = b256 + ((size_t)(h - 6) << 16); }
  const size_t hb = ((size_t)(b*8 + h)) << 18;
  const float SC = 0.125f * LOG2E;

  char* pw = (char*)Pp[w];
  bf16x8 ones8;
  #pragma unroll
  for (int e = 0; e < 8; e++) ones8[e] = (short)0x3F80;    // bf16 1.0

  bf16x8 qf[2][2];
  #pragma unroll
  for (int mf = 0; mf < 2; mf++){
    int qt = w*32 + mf*16 + lr;
    int n = (h == 0) ? (win*256 + qt) : map16(win, qt);
    const unsigned short* qp = qb + hb + ((size_t)n << 6) + lg*8;
    qf[mf][0] = *(const bf16x8*)qp;
    qf[mf][1] = *(const bf16x8*)(qp + 32);
  }
  f32x4 ao[2][4] = {};
  f32x4 lsum4[2] = {};

  for (int s = s0; s < s1; s++){
    // QK^T: K fragments straight from global (d-contiguous 16B)
    f32x4 sv[2][4] = {};
    #pragma unroll
    for (int kt = 0; kt < 2; kt++){
      bf16x8 kf[4];
      #pragma unroll
      for (int nf = 0; nf < 4; nf++){
        int tk = s*64 + nf*16 + lr;
        int nk = (h == 0) ? tk : map16(win, tk);
        kf[nf] = *(const bf16x8*)(kb + hb + ((size_t)nk << 6) + kt*32 + lg*8);
      }
      #pragma unroll
      for (int mf = 0; mf < 2; mf++)
        #pragma unroll
        for (int nf = 0; nf < 4; nf++)
          sv[mf][nf] = MFMA(qf[mf][kt], kf[nf], sv[mf][nf]);
    }
    // base-2 softmax (no shift) + cvt_pk pack -> wave-private LDS (swizzled)
    #pragma unroll
    for (int mf = 0; mf < 2; mf++)
      #pragma unroll
      for (int nfp = 0; nfp < 2; nfp++)
        #pragma unroll
        for (int r = 0; r < 4; r++){
          int nfA = nfp*2, nfB = nfp*2 + 1;
          float xa, xb_;
          if (btab){
            int qw = w*32 + mf*16 + lg*4 + r;
            int kwA = s*64 + nfA*16 + lr, kwB = s*64 + nfB*16 + lr;
            xa = __builtin_fmaf(sv[mf][nfA][r], SC, btab[(qw << 8) + kwA]);
            xb_= __builtin_fmaf(sv[mf][nfB][r], SC, btab[(qw << 8) + kwB]);
          } else {
            xa = sv[mf][nfA][r] * SC;
            xb_= sv[mf][nfB][r] * SC;
          }
          unsigned pk = cvt_pk_bf16(fast_exp2(xa), fast_exp2(xb_));
          int row = mf*16 + lg*4 + r;
          int swz = (row & 7) << 4;
          int cbA = ((nfA*16 + lr)*2) ^ swz;
          int cbB = ((nfB*16 + lr)*2) ^ swz;
          *(unsigned short*)(pw + row*128 + cbA) = (unsigned short)pk;
          *(unsigned short*)(pw + row*128 + cbB) = (unsigned short)(pk >> 16);
        }
    // PV: V^T fragments straight from global (n-contiguous 16B); lsum via ones-MFMA
    #pragma unroll
    for (int kg = 0; kg < 2; kg++){
      bf16x8 pa[2], vf[4];
      #pragma unroll
      for (int mf = 0; mf < 2; mf++){
        int row = mf*16 + lr;
        int cb  = (kg*64 + lg*16) ^ ((row & 7) << 4);
        pa[mf] = *(const bf16x8*)(pw + row*128 + cb);
      }
      int tv = s*64 + kg*32 + lg*8;
      int nv = (h == 0) ? tv : map16(win, tv);
      #pragma unroll
      for (int df = 0; df < 4; df++)
        vf[df] = *(const bf16x8*)(vtb + hb + ((size_t)(df*16 + lr) << 12) + nv);
      #pragma unroll
      for (int mf = 0; mf < 2; mf++){
        #pragma unroll
        for (int df = 0; df < 4; df++)
          ao[mf][df] = MFMA(pa[mf], vf[kg == 0 ? df : df], ao[mf][df]);
        lsum4[mf] = MFMA(pa[mf], ones8, lsum4[mf]);
      }
    }
  }

  if (h == 0){
    #pragma unroll
    for (int mf = 0; mf < 2; mf++)
      #pragma unroll
      for (int r = 0; r < 4; r++){
        int qt = w*32 + mf*16 + lg*4 + r;
        size_t rowb = (((size_t)(b*8 + chunk)) << 12) + win*256 + qt;
        if (lr == 0) pl[rowb] = lsum4[mf][r];
        #pragma unroll
        for (int df = 0; df < 4; df++)
          pO[(rowb << 6) + df*16 + lr] = f2bf(ao[mf][df][r]);
      }
  } else {
    #pragma unroll
    for (int mf = 0; mf < 2; mf++)
      #pragma unroll
      for (int df = 0; df < 4; df++)
        #pragma unroll
        for (int r = 0; r < 4; r++){
          float o = ao[mf][df][r] / lsum4[mf][r];
          int qt = w*32 + mf*16 + lg*4 + r;
          int np2 = win*256 + qt;
          size_t base = (((size_t)b*4096 + np2) << 9) + h*64 + df*16 + lr;
          fsp[base] = f2bf(o);
        }
  }
}

// ---------- combine head-0 KV chunks (plain sums) ----------
__global__ __launch_bounds__(256)
void k_comb(const unsigned short* __restrict__ pO, const float* __restrict__ pl,
            unsigned short* __restrict__ fsp){
  int tid = blockIdx.x*256 + threadIdx.x;      // 2M = 32768 rows * 64 d
  int d = tid & 63;
  int row = tid >> 6;
  int b = row >> 12;
  int n = row & 4095;
  float o = 0.f, L = 0.f;
  #pragma unroll
  for (int c = 0; c < 8; c++){
    size_t rr = (((size_t)(b*8 + c)) << 12) + n;
    L += pl[rr];
    o += bf2f(pO[(rr << 6) + d]);
  }
  o /= L;
  fsp[(((size_t)b*4096 + n) << 9) + d] = f2bf(o);
}

// ---------- 64-token window attention (heads 1..5), base-2 softmax ----------
__device__ __forceinline__ int mapw(int h, int u, int t){
  if (h <= 2) return (((u >> 2)*4 + (t >> 4)) << 6) + ((u & 3) << 4) + (t & 15);
  return (((u >> 3)*8 + (t >> 3)) << 6) + ((u & 7) << 3) + (t & 7);
}

__global__ __launch_bounds__(256, 2)
void k_win64(const unsigned short* __restrict__ qb, const unsigned short* __restrict__ kb,
             const unsigned short* __restrict__ vtb, const float* __restrict__ b64,
             unsigned short* __restrict__ fsp)
{
  __shared__ unsigned short KP[4][64*64];
  __shared__ unsigned short Vw[4][64*64];
  const int t = threadIdx.x, l = t & 63, w = t >> 6;
  const int lr = l & 15, lg = l >> 4;
  const int gid = blockIdx.x*4 + w;
  const int b = gid / 320;
  const int rem = gid % 320;
  const int h = 1 + (rem >> 6);
  const int u = rem & 63;
  const size_t hb = ((size_t)(b*8 + h)) << 18;
  const float SC = 0.125f * LOG2E;

  #pragma unroll
  for (int i = 0; i < 8; i++){
    int row = i*8 + (l >> 3);
    int sc  = (((l & 7) ^ (row & 7)) << 3);
    gload16(kb  + hb + ((size_t)mapw(h,u,row) << 6) + sc, &KP[w][i*512]);
    gload16(vtb + hb + ((size_t)row << 12) + mapw(h,u,sc), &Vw[w][i*512]);
  }
  bf16x8 qf[4][2];
  #pragma unroll
  for (int mf = 0; mf < 4; mf++){
    int n = mapw(h, u, mf*16 + lr);
    const unsigned short* qp = qb + hb + ((size_t)n << 6) + lg*8;
    qf[mf][0] = *(const bf16x8*)qp;
    qf[mf][1] = *(const bf16x8*)(qp + 32);
  }
  __syncthreads();

  const char* kpc = (const char*)KP[w];
  const char* vwc = (const char*)Vw[w];
  f32x4 sv[4][4] = {};
  #pragma unroll
  for (int kt = 0; kt < 2; kt++){
    bf16x8 kf[4];
    #pragma unroll
    for (int nf = 0; nf < 4; nf++){
      int row = nf*16 + lr;
      int cb  = (kt*64 + lg*16) ^ ((row & 7) << 4);
      kf[nf] = *(const bf16x8*)(kpc + row*128 + cb);
    }
    #pragma unroll
    for (int mf = 0; mf < 4; mf++)
      #pragma unroll
      for (int nf = 0; nf < 4; nf++)
        sv[mf][nf] = MFMA(qf[mf][kt], kf[nf], sv[mf][nf]);
  }
  const float* bt = b64 + ((size_t)(h-1) << 12);
  float li[4][4];
  #pragma unroll
  for (int mf = 0; mf < 4; mf++)
    #pragma unroll
    for (int r = 0; r < 4; r++){
      int qt = mf*16 + lg*4 + r;
      #pragma unroll
      for (int nf = 0; nf < 4; nf++)
        sv[mf][nf][r] = __builtin_fmaf(sv[mf][nf][r], SC, bt[(qt << 6) + nf*16 + lr]);
      float mx = fmaxf(fmaxf(sv[mf][0][r], sv[mf][1][r]), fmaxf(sv[mf][2][r], sv[mf][3][r]));
      mx = fmaxf(mx, __shfl_xor(mx, 1));
      mx = fmaxf(mx, __shfl_xor(mx, 2));
      mx = fmaxf(mx, __shfl_xor(mx, 4));
      mx = fmaxf(mx, __shfl_xor(mx, 8));
      float rs = 0.f;
      #pragma unroll
      for (int nf = 0; nf < 4; nf++){
        float p = fast_exp2(sv[mf][nf][r] - mx);
        sv[mf][nf][r] = p; rs += p;
      }
      rs += __shfl_xor(rs, 1); rs += __shfl_xor(rs, 2);
      rs += __shfl_xor(rs, 4); rs += __shfl_xor(rs, 8);
      li[mf][r] = rs;
    }
  char* pw = (char*)KP[w];
  #pragma unroll
  for (int mf = 0; mf < 4; mf++)
    #pragma unroll
    for (int nf = 0; nf < 4; nf++)
      #pragma unroll
      for (int r = 0; r < 4; r++){
        int row = mf*16 + lg*4 + r;
        int cb  = ((nf*16 + lr)*2) ^ ((row & 7) << 4);
        *(unsigned short*)(pw + row*128 + cb) = f2bf(sv[mf][nf][r]);
      }
  f32x4 ao[4][4] = {};
  #pragma unroll
  for (int kg = 0; kg < 2; kg++){
    bf16x8 pa[4], vf[4];
    #pragma unroll
    for (int mf = 0; mf < 4; mf++){
      int row = mf*16 + lr;
      int cb  = (kg*64 + lg*16) ^ ((row & 7) << 4);
      pa[mf] = *(const bf16x8*)(pw + row*128 + cb);
    }
    #pragma unroll
    for (int df = 0; df < 4; df++){
      int row = df*16 + lr;
      int cb  = (kg*64 + lg*16) ^ ((row & 7) << 4);
      vf[df] = *(const bf16x8*)(vwc + row*128 + cb);
    }
    #pragma unroll
    for (int mf = 0; mf < 4; mf++)
      #pragma unroll
      for (int df = 0; df < 4; df++)
        ao[mf][df] = MFMA(pa[mf], vf[df], ao[mf][df]);
  }
  #pragma unroll
  for (int mf = 0; mf < 4; mf++)
    #pragma unroll
    for (int df = 0; df < 4; df++)
      #pragma unroll
      for (int r = 0; r < 4; r++){
        float o = ao[mf][df][r] / li[mf][r];
        int qt = mf*16 + lg*4 + r;
        int np;
        if (h <= 2){
          int r4 = qt >> 4, w_ = (qt >> 2) & 3, c = qt & 3;
          np = (u >> 2)*256 + (u & 3)*64 + w_*16 + r4*4 + c;
        } else {
          np = u*64 + qt;
        }
        fsp[(((size_t)b*4096 + np) << 9) + h*64 + df*16 + lr] = f2bf(o);
      }
}

// ---------- launch ----------
extern "C" void kernel_launch(void* const* d_in, const int* in_sizes, int n_in,
                              void* d_out, int out_size, void* d_ws, size_t ws_size,
                              hipStream_t stream) {
  const float* x     = (const float*)d_in[0];
  const float* Wq    = (const float*)d_in[1];
  const float* Wkv   = (const float*)d_in[2];
  const float* Wp    = (const float*)d_in[3];
  const float* bproj = (const float*)d_in[4];
  const float* t1 = (const float*)d_in[7];
  const float* t2 = (const float*)d_in[8];
  const float* t3 = (const float*)d_in[9];
  const float* t4 = (const float*)d_in[10];
  const float* t5 = (const float*)d_in[11];
  const float* t6 = (const float*)d_in[12];
  const float* t7 = (const float*)d_in[13];

  char* W = (char*)d_ws;
  size_t off = 0;
  auto alloc = [&](size_t bytes)->char*{
    char* p = W + off; off += (bytes + 255) & ~(size_t)255; return p;
  };
  unsigned short* xb   = (unsigned short*)alloc((size_t)32768*512*2);   // dead after gemm0
  unsigned short* wqkv = (unsigned short*)alloc((size_t)1536*512*2);    // dead after gemm0
  unsigned short* wsp  = (unsigned short*)alloc((size_t)512*512*2);
  unsigned short* qbuf = (unsigned short*)alloc((size_t)8*8*4096*64*2);
  unsigned short* kbuf = (unsigned short*)alloc((size_t)8*8*4096*64*2);
  unsigned short* vtb  = (unsigned short*)alloc((size_t)8*8*4096*64*2);
  unsigned short* fsp  = (unsigned short*)alloc((size_t)32768*512*2);
  float* b64  = (float*)alloc((size_t)5*64*64*4);
  float* b256 = (float*)alloc((size_t)2*256*256*4);
  if (off > ws_size) return;

  // head-0 partials alias dead regions (flash runs after gemm0):
  unsigned short* pO = xb;                 // (8b*8c)*4096 rows * 64 d * 2B = 32 MiB
  float* pl = (float*)wqkv;                // 64*4096*4B = 1 MiB

  k_conv_x<<<8192, 256, 0, stream>>>(x, xb, 32768*512);
  k_conv_w<<<640, 256, 0, stream>>>(Wq, Wkv, Wp, wqkv, wsp);
  k_bias<<<64, 256, 0, stream>>>(t1,t2,t3,t4,t5,t6,t7, b64, b256);

  k_gemm<0><<<3072, 256, 0, stream>>>(xb, wqkv, 32768,
                                      qbuf, kbuf, vtb, nullptr, nullptr);
  k_flash<<<1280, 512, 0, stream>>>(qbuf, kbuf, vtb, b256, fsp, pO, pl);
  k_comb<<<8192, 256, 0, stream>>>(pO, pl, fsp);
  k_win64<<<640, 256, 0, stream>>>(qbuf, kbuf, vtb, b64, fsp);
  k_gemm<1><<<1024, 256, 0, stream>>>(fsp, wsp, 32768,
                                      nullptr, nullptr, nullptr, (float*)d_out, bproj);
}